// Round 2
// baseline (30996.497 us; speedup 1.0000x reference)
//
#include <hip/hip_runtime.h>
#include <math.h>

#define N_NODES 20000
#define E_EDGES 200000
#define M1 60000            // layer-1 node count (3*N)

// ---------------------------------------------------------------------------
// GEMM: C[M,256] = X[M,K] @ W[K,256]   (K = 64 or 256, M multiple of 16)
// block 256 threads: 4 row-groups x 64 cols; each thread 4 rows x 4 cols.
// ---------------------------------------------------------------------------
template<int K>
__global__ __launch_bounds__(256) void gemm_proj(const float* __restrict__ X,
                                                 const float* __restrict__ W,
                                                 float* __restrict__ C) {
    __shared__ float Xs[16][K];
    const int row0 = blockIdx.x * 16;
    const int tid = threadIdx.x;
    for (int idx = tid; idx < 16 * K; idx += 256) {
        int r = idx / K, k = idx - r * K;
        Xs[r][k] = X[(row0 + r) * K + k];
    }
    __syncthreads();
    const int jj = tid & 63;
    const int rg = tid >> 6;  // 0..3
    float acc[4][4];
#pragma unroll
    for (int r = 0; r < 4; ++r)
#pragma unroll
        for (int t = 0; t < 4; ++t) acc[r][t] = 0.f;
    for (int k = 0; k < K; ++k) {
        float wv[4];
#pragma unroll
        for (int t = 0; t < 4; ++t) wv[t] = W[k * 256 + jj + 64 * t];
#pragma unroll
        for (int r = 0; r < 4; ++r) {
            float xv = Xs[rg * 4 + r][k];
#pragma unroll
            for (int t = 0; t < 4; ++t) acc[r][t] += xv * wv[t];
        }
    }
#pragma unroll
    for (int r = 0; r < 4; ++r)
#pragma unroll
        for (int t = 0; t < 4; ++t)
            C[(row0 + rg * 4 + r) * 256 + jj + 64 * t] = acc[r][t];
}

// ---------------------------------------------------------------------------
// x1[(i*N+v)*256 + c] = theta0[c]*proj0[v*256+c] + bias0[c]   (i = 0..2)
// ---------------------------------------------------------------------------
__global__ void init_x1(const float* __restrict__ proj0,
                        const float* __restrict__ theta,
                        const float* __restrict__ bias,
                        float* __restrict__ x1) {
    int idx = blockIdx.x * 256 + threadIdx.x;  // over N*256
    if (idx >= N_NODES * 256) return;
    int c = idx & 255;
    float v = theta[c] * proj0[idx] + bias[c];
    x1[idx] = v;
    x1[N_NODES * 256 + idx] = v;
    x1[2 * N_NODES * 256 + idx] = v;
}

// ---------------------------------------------------------------------------
// out[(i*M1+v)*64+f] = 0.25*sum_h theta1[h*64+f]*proj1[v*256+h*64+f] + bias1[f]
// ---------------------------------------------------------------------------
__global__ void init_out(const float* __restrict__ proj1,
                         const float* __restrict__ theta,
                         const float* __restrict__ bias,
                         float* __restrict__ out) {
    int idx = blockIdx.x * 256 + threadIdx.x;  // over M1*64
    if (idx >= M1 * 64) return;
    int v = idx >> 6, f = idx & 63;
    float s = 0.f;
#pragma unroll
    for (int h = 0; h < 4; ++h) s += theta[h * 64 + f] * proj1[v * 256 + h * 64 + f];
    float val = 0.25f * s + bias[f];
    out[idx] = val;
    out[M1 * 64 + idx] = val;
    out[2 * M1 * 64 + idx] = val;
}

__global__ void sigmoid_k(float4* __restrict__ x, int n4) {
    int i = blockIdx.x * 256 + threadIdx.x;
    if (i >= n4) return;
    float4 v = x[i];
    v.x = 1.f / (1.f + expf(-v.x));
    v.y = 1.f / (1.f + expf(-v.y));
    v.z = 1.f / (1.f + expf(-v.z));
    v.w = 1.f / (1.f + expf(-v.w));
    x[i] = v;
}

// ---------------------------------------------------------------------------
// Attention: alpha[e] (float4 over heads).  1 wave = 1 edge.
// ---------------------------------------------------------------------------
__global__ __launch_bounds__(256) void att_kernel(const float* __restrict__ proj,
                                                  const int* __restrict__ ei,
                                                  const float* __restrict__ aW1,
                                                  const float* __restrict__ ab1,
                                                  const float* __restrict__ aW2,
                                                  const float* __restrict__ ab2,
                                                  float4* __restrict__ alpha) {
    __shared__ float W1s[192 * 64];
    __shared__ float b1s[64];
    __shared__ float W2s[64];
    const int tid = threadIdx.x;
    for (int i = tid; i < 192 * 64; i += 256) W1s[i] = aW1[i];
    if (tid < 64) { b1s[tid] = ab1[tid]; W2s[tid] = aW2[tid]; }
    __syncthreads();
    const int e = blockIdx.x * 4 + (tid >> 6);
    const int lane = tid & 63;
    if (e >= E_EDGES) return;
    const int vd = ei[e];
    const int vm = ei[E_EDGES + e];
    const int vs = ei[2 * E_EDGES + e];
    const float* pd = proj + vd * 256;
    const float* pm = proj + vm * 256;
    const float* ps = proj + vs * 256;
    float dh[4], mh[4], sh[4];
#pragma unroll
    for (int h = 0; h < 4; ++h) {
        dh[h] = pd[h * 64 + lane];
        mh[h] = pm[h * 64 + lane];
        sh[h] = ps[h * 64 + lane];
    }
    const float b2 = ab2[0];
    float sc[4];
#pragma unroll
    for (int h = 0; h < 4; ++h) {
        float acc = b1s[lane];
#pragma unroll
        for (int k = 0; k < 64; ++k) {
            acc += __shfl(dh[h], k) * W1s[k * 64 + lane];
            acc += __shfl(mh[h], k) * W1s[(64 + k) * 64 + lane];
            acc += __shfl(sh[h], k) * W1s[(128 + k) * 64 + lane];
        }
        acc = fmaxf(acc, 0.f);
        float v = acc * W2s[lane];
#pragma unroll
        for (int off = 32; off > 0; off >>= 1) v += __shfl_xor(v, off);
        v += b2;
        sc[h] = (v >= 0.f) ? v : 0.2f * v;  // leaky_relu 0.2
    }
    float mx = fmaxf(fmaxf(sc[0], sc[1]), fmaxf(sc[2], sc[3]));
    float e0 = expf(sc[0] - mx), e1 = expf(sc[1] - mx);
    float e2 = expf(sc[2] - mx), e3 = expf(sc[3] - mx);
    float inv = 1.f / (e0 + e1 + e2 + e3);
    if (lane == 0) alpha[e] = make_float4(e0 * inv, e1 * inv, e2 * inv, e3 * inv);
}

// ---------------------------------------------------------------------------
// Pair MLPs + scatter. LAYER 0: per-head atomicAdd into x1 (concat layout).
// LAYER 1: head-mean pre-reduced in-register, atomicAdd into out.
// 1 wave = 1 edge, 3 pairs x 4 heads inside.
// ---------------------------------------------------------------------------
template<int LAYER>
__global__ __launch_bounds__(256) void scatter_kernel(const float* __restrict__ proj,
                                                      const int* __restrict__ ei,
                                                      const float* __restrict__ eW1,
                                                      const float* __restrict__ eb1,
                                                      const float* __restrict__ eW2,
                                                      const float* __restrict__ eb2,
                                                      const float4* __restrict__ alpha,
                                                      float* __restrict__ out) {
    __shared__ float W1s[128 * 64];
    __shared__ float W2s[64 * 64];
    __shared__ float b1s[64], b2s[64];
    const int tid = threadIdx.x;
    for (int i = tid; i < 128 * 64; i += 256) W1s[i] = eW1[i];
    for (int i = tid; i < 64 * 64; i += 256) W2s[i] = eW2[i];
    if (tid < 64) { b1s[tid] = eb1[tid]; b2s[tid] = eb2[tid]; }
    __syncthreads();
    const int e = blockIdx.x * 4 + (tid >> 6);
    const int lane = tid & 63;
    if (e >= E_EDGES) return;
    const int vd = ei[e];
    const int vm = ei[E_EDGES + e];
    const int vs = ei[2 * E_EDGES + e];
    const float* pd = proj + vd * 256;
    const float* pm = proj + vm * 256;
    const float* ps = proj + vs * 256;
    float dh[4], mh[4], sh[4];
#pragma unroll
    for (int h = 0; h < 4; ++h) {
        dh[h] = pd[h * 64 + lane];
        mh[h] = pm[h * 64 + lane];
        sh[h] = ps[h * 64 + lane];
    }
    const float4 al = alpha[e];
    const float alh[4] = {al.x, al.y, al.z, al.w};
    const int vt[3] = {vd, vm, vs};
#pragma unroll
    for (int p = 0; p < 3; ++p) {
        float accsum = 0.f;
#pragma unroll
        for (int h = 0; h < 4; ++h) {
            // pairs: p0=(m,s) p1=(d,s) p2=(d,m)
            float A = (p == 0) ? mh[h] : dh[h];
            float B = (p == 2) ? mh[h] : sh[h];
            float acc = b1s[lane];
#pragma unroll
            for (int k = 0; k < 64; ++k) {
                acc += __shfl(A, k) * W1s[k * 64 + lane];
                acc += __shfl(B, k) * W1s[(64 + k) * 64 + lane];
            }
            acc = (acc >= 0.f) ? acc : 0.2f * acc;  // leaky 0.2
            float o = b2s[lane];
#pragma unroll
            for (int k = 0; k < 64; ++k) o += __shfl(acc, k) * W2s[k * 64 + lane];
            if (LAYER == 0) {
                atomicAdd(&out[(p * N_NODES + vt[p]) * 256 + h * 64 + lane], alh[h] * o);
            } else {
                accsum += alh[h] * o;
            }
        }
        if (LAYER == 1) {
            atomicAdd(&out[(p * M1 + vt[p]) * 64 + lane], 0.25f * accsum);
        }
    }
}

// ---------------------------------------------------------------------------
extern "C" void kernel_launch(void* const* d_in, const int* in_sizes, int n_in,
                              void* d_out, int out_size, void* d_ws, size_t ws_size,
                              hipStream_t stream) {
    (void)in_sizes; (void)n_in; (void)out_size; (void)ws_size;
    const float* x0       = (const float*)d_in[0];
    const int* ei         = (const int*)d_in[1];   // harness passes integers as int32
    const float* p0_Wp    = (const float*)d_in[2];
    const float* p0_aW1   = (const float*)d_in[3];
    const float* p0_ab1   = (const float*)d_in[4];
    const float* p0_aW2   = (const float*)d_in[5];
    const float* p0_ab2   = (const float*)d_in[6];
    const float* p0_eW1   = (const float*)d_in[7];
    const float* p0_eb1   = (const float*)d_in[8];
    const float* p0_eW2   = (const float*)d_in[9];
    const float* p0_eb2   = (const float*)d_in[10];
    const float* p0_theta = (const float*)d_in[11];
    const float* p0_bias  = (const float*)d_in[12];
    const float* p1_Wp    = (const float*)d_in[13];
    const float* p1_aW1   = (const float*)d_in[14];
    const float* p1_ab1   = (const float*)d_in[15];
    const float* p1_aW2   = (const float*)d_in[16];
    const float* p1_ab2   = (const float*)d_in[17];
    const float* p1_eW1   = (const float*)d_in[18];
    const float* p1_eb1   = (const float*)d_in[19];
    const float* p1_eW2   = (const float*)d_in[20];
    const float* p1_eb2   = (const float*)d_in[21];
    const float* p1_theta = (const float*)d_in[22];
    const float* p1_bias  = (const float*)d_in[23];

    // Workspace layout (proj1 aliases proj0 — proj0 dead after layer-0):
    //   bufA  : max(proj0, proj1) = 15,360,000 floats
    //   x1    : 15,360,000 floats
    //   alpha :    800,000 floats
    // total 31,520,000 floats = 126.1 MB
    float* ws = (float*)d_ws;
    float* proj0 = ws;
    float* proj1 = ws;                         // aliases proj0 (layer-0 dead)
    float* x1    = ws + 15360000;
    float4* alpha = (float4*)(ws + 30720000);
    float* out = (float*)d_out;                // 180000*64

    const int EB = (E_EDGES + 3) / 4;  // 4 edges (waves) per block

    // ---- layer 0 ----
    gemm_proj<64><<<N_NODES / 16, 256, 0, stream>>>(x0, p0_Wp, proj0);
    init_x1<<<(N_NODES * 256 + 255) / 256, 256, 0, stream>>>(proj0, p0_theta, p0_bias, x1);
    att_kernel<<<EB, 256, 0, stream>>>(proj0, ei, p0_aW1, p0_ab1, p0_aW2, p0_ab2, alpha);
    scatter_kernel<0><<<EB, 256, 0, stream>>>(proj0, ei, p0_eW1, p0_eb1, p0_eW2, p0_eb2, alpha, x1);
    sigmoid_k<<<(M1 * 64 + 255) / 256, 256, 0, stream>>>((float4*)x1, M1 * 64);  // M1*256/4 elems

    // ---- layer 1 ----
    gemm_proj<256><<<M1 / 16, 256, 0, stream>>>(x1, p1_Wp, proj1);
    init_out<<<(M1 * 64 + 255) / 256, 256, 0, stream>>>(proj1, p1_theta, p1_bias, out);
    att_kernel<<<EB, 256, 0, stream>>>(proj1, ei, p1_aW1, p1_ab1, p1_aW2, p1_ab2, alpha);
    scatter_kernel<1><<<EB, 256, 0, stream>>>(proj1, ei, p1_eW1, p1_eb1, p1_eW2, p1_eb2, alpha, out);
}

// Round 3
// 4471.984 us; speedup vs baseline: 6.9313x; 6.9313x over previous
//
#include <hip/hip_runtime.h>
#include <math.h>

#define N_NODES 20000
#define E_EDGES 200000
#define M1 60000            // layer-1 node count (3*N)
#define TE 16               // edges per block in fused kernel
#define TPAD 68             // padded tile row length (floats), 16B-aligned, breaks bank conflicts

// ---------------------------------------------------------------------------
// GEMM: C[M,256] = X[M,K] @ W[K,256]   (K = 64 or 256, M multiple of 16)
// ---------------------------------------------------------------------------
template<int K>
__global__ __launch_bounds__(256) void gemm_proj(const float* __restrict__ X,
                                                 const float* __restrict__ W,
                                                 float* __restrict__ C) {
    __shared__ float Xs[16][K];
    const int row0 = blockIdx.x * 16;
    const int tid = threadIdx.x;
    for (int idx = tid; idx < 16 * K; idx += 256) {
        int r = idx / K, k = idx - r * K;
        Xs[r][k] = X[(row0 + r) * K + k];
    }
    __syncthreads();
    const int jj = tid & 63;
    const int rg = tid >> 6;
    float acc[4][4];
#pragma unroll
    for (int r = 0; r < 4; ++r)
#pragma unroll
        for (int t = 0; t < 4; ++t) acc[r][t] = 0.f;
    for (int k = 0; k < K; ++k) {
        float wv[4];
#pragma unroll
        for (int t = 0; t < 4; ++t) wv[t] = W[k * 256 + jj + 64 * t];
#pragma unroll
        for (int r = 0; r < 4; ++r) {
            float xv = Xs[rg * 4 + r][k];
#pragma unroll
            for (int t = 0; t < 4; ++t) acc[r][t] += xv * wv[t];
        }
    }
#pragma unroll
    for (int r = 0; r < 4; ++r)
#pragma unroll
        for (int t = 0; t < 4; ++t)
            C[(row0 + rg * 4 + r) * 256 + jj + 64 * t] = acc[r][t];
}

__global__ void init_x1(const float* __restrict__ proj0,
                        const float* __restrict__ theta,
                        const float* __restrict__ bias,
                        float* __restrict__ x1) {
    int idx = blockIdx.x * 256 + threadIdx.x;
    if (idx >= N_NODES * 256) return;
    int c = idx & 255;
    float v = theta[c] * proj0[idx] + bias[c];
    x1[idx] = v;
    x1[N_NODES * 256 + idx] = v;
    x1[2 * N_NODES * 256 + idx] = v;
}

__global__ void init_out(const float* __restrict__ proj1,
                         const float* __restrict__ theta,
                         const float* __restrict__ bias,
                         float* __restrict__ out) {
    int idx = blockIdx.x * 256 + threadIdx.x;
    if (idx >= M1 * 64) return;
    int v = idx >> 6, f = idx & 63;
    float s = 0.f;
#pragma unroll
    for (int h = 0; h < 4; ++h) s += theta[h * 64 + f] * proj1[v * 256 + h * 64 + f];
    float val = 0.25f * s + bias[f];
    out[idx] = val;
    out[M1 * 64 + idx] = val;
    out[2 * M1 * 64 + idx] = val;
}

__global__ void sigmoid_k(float4* __restrict__ x, int n4) {
    int i = blockIdx.x * 256 + threadIdx.x;
    if (i >= n4) return;
    float4 v = x[i];
    v.x = 1.f / (1.f + expf(-v.x));
    v.y = 1.f / (1.f + expf(-v.y));
    v.z = 1.f / (1.f + expf(-v.z));
    v.w = 1.f / (1.f + expf(-v.w));
    x[i] = v;
}

// ---------------------------------------------------------------------------
// One 64-wide K-section of the tile GEMM.
// A: LDS tile, rows padded to TPAD, this thread reads rows ty*4..ty*4+3
// (broadcast across the 16 tx lanes of the ty-group).
// W: LDS [64][64] (k-major), lane reads cols tx*4..tx*4+3.
// acc[r][c] += sum_k A[ty*4+r][k] * W[k][tx*4+c]
// ---------------------------------------------------------------------------
__device__ __forceinline__ void fma_rank1(float acc[4], float a, const float4 w) {
    acc[0] = fmaf(a, w.x, acc[0]);
    acc[1] = fmaf(a, w.y, acc[1]);
    acc[2] = fmaf(a, w.z, acc[2]);
    acc[3] = fmaf(a, w.w, acc[3]);
}

__device__ __forceinline__ void gemm_sec(const float* __restrict__ A,
                                         const float* __restrict__ W,
                                         int ty, int tx, float acc[4][4]) {
#pragma unroll 4
    for (int k = 0; k < 64; k += 4) {
        float4 a0 = *(const float4*)(A + (ty * 4 + 0) * TPAD + k);
        float4 a1 = *(const float4*)(A + (ty * 4 + 1) * TPAD + k);
        float4 a2 = *(const float4*)(A + (ty * 4 + 2) * TPAD + k);
        float4 a3 = *(const float4*)(A + (ty * 4 + 3) * TPAD + k);
        float4 w0 = *(const float4*)(W + (k + 0) * 64 + tx * 4);
        float4 w1 = *(const float4*)(W + (k + 1) * 64 + tx * 4);
        float4 w2 = *(const float4*)(W + (k + 2) * 64 + tx * 4);
        float4 w3 = *(const float4*)(W + (k + 3) * 64 + tx * 4);
        fma_rank1(acc[0], a0.x, w0); fma_rank1(acc[0], a0.y, w1);
        fma_rank1(acc[0], a0.z, w2); fma_rank1(acc[0], a0.w, w3);
        fma_rank1(acc[1], a1.x, w0); fma_rank1(acc[1], a1.y, w1);
        fma_rank1(acc[1], a1.z, w2); fma_rank1(acc[1], a1.w, w3);
        fma_rank1(acc[2], a2.x, w0); fma_rank1(acc[2], a2.y, w1);
        fma_rank1(acc[2], a2.z, w2); fma_rank1(acc[2], a2.w, w3);
        fma_rank1(acc[3], a3.x, w0); fma_rank1(acc[3], a3.y, w1);
        fma_rank1(acc[3], a3.z, w2); fma_rank1(acc[3], a3.w, w3);
    }
}

// ---------------------------------------------------------------------------
// Fused per-layer edge kernel: gather d/m/s -> attention MLP -> softmax
// -> 3 pair MLPs -> alpha-weighted atomic scatter.
// Block: 16 edges, 64 rows (row = e*4 + h), 256 threads (ty 0..15, tx 0..15).
// Thread (ty,tx) owns rows of edge ty (all 4 heads) x cols tx*4..tx*4+3.
// ---------------------------------------------------------------------------
template<int LAYER>
__global__ __launch_bounds__(256) void fused_edge(const float* __restrict__ proj,
                                                  const int* __restrict__ ei,
                                                  const float* __restrict__ aW1,
                                                  const float* __restrict__ ab1,
                                                  const float* __restrict__ aW2,
                                                  const float* __restrict__ ab2,
                                                  const float* __restrict__ eW1,
                                                  const float* __restrict__ eb1,
                                                  const float* __restrict__ eW2,
                                                  const float* __restrict__ eb2,
                                                  float* __restrict__ out) {
    __shared__ float sAW1[192 * 64];          // att W1; first 64*TPAD floats reused as nb1
    __shared__ float sEW1[128 * 64];
    __shared__ float sEW2[64 * 64];
    __shared__ float sT[3][64 * TPAD];        // gathered d,m,s tiles (rows padded)

    const int tid = threadIdx.x;
    const int ty = tid >> 4, tx = tid & 15;
    const int wv = tid >> 6, lane = tid & 63;
    const int e0 = blockIdx.x * TE;

    // ---- stage weights (vectorized) ----
    {
        const float4* s1 = (const float4*)aW1;
        for (int i = tid; i < 192 * 64 / 4; i += 256) ((float4*)sAW1)[i] = s1[i];
        const float4* s2 = (const float4*)eW1;
        for (int i = tid; i < 128 * 64 / 4; i += 256) ((float4*)sEW1)[i] = s2[i];
        const float4* s3 = (const float4*)eW2;
        for (int i = tid; i < 64 * 64 / 4; i += 256) ((float4*)sEW2)[i] = s3[i];
    }
    // ---- gather d/m/s: 48 segments (role,edge), each one 1KB proj row ----
    for (int seg = wv; seg < 48; seg += 4) {
        const int ro = seg >> 4, e = seg & 15;
        const int v = ei[ro * E_EDGES + e0 + e];
        const float4 src = *(const float4*)(proj + (size_t)v * 256 + lane * 4);
        *(float4*)(&sT[ro][(e * 4 + (lane >> 4)) * TPAD + (lane & 15) * 4]) = src;
    }
    __syncthreads();

    // ---- attention MLP: acc = inter @ aW1 (K=192) ----
    float acc[4][4];
#pragma unroll
    for (int r = 0; r < 4; ++r)
#pragma unroll
        for (int c = 0; c < 4; ++c) acc[r][c] = 0.f;
    for (int ks = 0; ks < 3; ++ks)
        gemm_sec(sT[ks], sAW1 + ks * 4096, ty, tx, acc);

    // epilogue: +ab1, relu, @aW2, allreduce over tx, +ab2, leaky, softmax
    float alr[4];
    {
        float b1c[4], w2c[4];
#pragma unroll
        for (int c = 0; c < 4; ++c) { b1c[c] = ab1[tx * 4 + c]; w2c[c] = aW2[tx * 4 + c]; }
        float p_[4];
#pragma unroll
        for (int r = 0; r < 4; ++r) {
            float s = 0.f;
#pragma unroll
            for (int c = 0; c < 4; ++c) {
                float hv = fmaxf(acc[r][c] + b1c[c], 0.f);
                s = fmaf(hv, w2c[c], s);
            }
            p_[r] = s;
        }
#pragma unroll
        for (int off = 1; off < 16; off <<= 1) {
#pragma unroll
            for (int r = 0; r < 4; ++r) p_[r] += __shfl_xor(p_[r], off);
        }
        const float b2 = ab2[0];
        float sc[4];
#pragma unroll
        for (int r = 0; r < 4; ++r) {
            float v = p_[r] + b2;
            sc[r] = (v >= 0.f) ? v : 0.2f * v;
        }
        float mx = fmaxf(fmaxf(sc[0], sc[1]), fmaxf(sc[2], sc[3]));
        float ex[4], sum = 0.f;
#pragma unroll
        for (int r = 0; r < 4; ++r) { ex[r] = expf(sc[r] - mx); sum += ex[r]; }
        float inv = 1.f / sum;
#pragma unroll
        for (int r = 0; r < 4; ++r) alr[r] = ex[r] * inv;
    }
    __syncthreads();  // aW1 reads done; its LDS becomes nb1

    float* nb1 = sAW1;  // [64][TPAD] overlay

    // this thread's edge node ids
    const int vd = ei[e0 + ty];
    const int vm = ei[E_EDGES + e0 + ty];
    const int vs = ei[2 * E_EDGES + e0 + ty];
    const int vt[3] = {vd, vm, vs};

    float eb1c[4], eb2c[4];
#pragma unroll
    for (int c = 0; c < 4; ++c) { eb1c[c] = eb1[tx * 4 + c]; eb2c[c] = eb2[tx * 4 + c]; }

#pragma unroll 1
    for (int p = 0; p < 3; ++p) {
        // pairs: p0=(m,s) p1=(d,s) p2=(d,m)
        const float* Asec = (p == 0) ? sT[1] : sT[0];
        const float* Bsec = (p == 2) ? sT[1] : sT[2];
        float a1[4][4];
#pragma unroll
        for (int r = 0; r < 4; ++r)
#pragma unroll
            for (int c = 0; c < 4; ++c) a1[r][c] = 0.f;
        gemm_sec(Asec, sEW1, ty, tx, a1);
        gemm_sec(Bsec, sEW1 + 4096, ty, tx, a1);
        // bias + leaky -> nb1
#pragma unroll
        for (int r = 0; r < 4; ++r) {
            float4 v;
            float t0 = a1[r][0] + eb1c[0]; v.x = (t0 >= 0.f) ? t0 : 0.2f * t0;
            float t1 = a1[r][1] + eb1c[1]; v.y = (t1 >= 0.f) ? t1 : 0.2f * t1;
            float t2 = a1[r][2] + eb1c[2]; v.z = (t2 >= 0.f) ? t2 : 0.2f * t2;
            float t3 = a1[r][3] + eb1c[3]; v.w = (t3 >= 0.f) ? t3 : 0.2f * t3;
            *(float4*)(&nb1[(ty * 4 + r) * TPAD + tx * 4]) = v;
        }
        __syncthreads();
        float a2[4][4];
#pragma unroll
        for (int r = 0; r < 4; ++r)
#pragma unroll
            for (int c = 0; c < 4; ++c) a2[r][c] = 0.f;
        gemm_sec(nb1, sEW2, ty, tx, a2);
        // alpha-weighted scatter
        if (LAYER == 0) {
            float* dst = out + ((size_t)(p * N_NODES + vt[p])) * 256 + tx * 4;
#pragma unroll
            for (int r = 0; r < 4; ++r)
#pragma unroll
                for (int c = 0; c < 4; ++c)
                    atomicAdd(dst + r * 64 + c, alr[r] * (a2[r][c] + eb2c[c]));
        } else {
            float* dst = out + ((size_t)(p * M1 + vt[p])) * 64 + tx * 4;
#pragma unroll
            for (int c = 0; c < 4; ++c) {
                float s = 0.f;
#pragma unroll
                for (int r = 0; r < 4; ++r) s += alr[r] * (a2[r][c] + eb2c[c]);
                atomicAdd(dst + c, 0.25f * s);
            }
        }
        __syncthreads();  // nb1 reused next pair
    }
}

// ---------------------------------------------------------------------------
extern "C" void kernel_launch(void* const* d_in, const int* in_sizes, int n_in,
                              void* d_out, int out_size, void* d_ws, size_t ws_size,
                              hipStream_t stream) {
    (void)in_sizes; (void)n_in; (void)out_size; (void)ws_size;
    const float* x0       = (const float*)d_in[0];
    const int* ei         = (const int*)d_in[1];
    const float* p0_Wp    = (const float*)d_in[2];
    const float* p0_aW1   = (const float*)d_in[3];
    const float* p0_ab1   = (const float*)d_in[4];
    const float* p0_aW2   = (const float*)d_in[5];
    const float* p0_ab2   = (const float*)d_in[6];
    const float* p0_eW1   = (const float*)d_in[7];
    const float* p0_eb1   = (const float*)d_in[8];
    const float* p0_eW2   = (const float*)d_in[9];
    const float* p0_eb2   = (const float*)d_in[10];
    const float* p0_theta = (const float*)d_in[11];
    const float* p0_bias  = (const float*)d_in[12];
    const float* p1_Wp    = (const float*)d_in[13];
    const float* p1_aW1   = (const float*)d_in[14];
    const float* p1_ab1   = (const float*)d_in[15];
    const float* p1_aW2   = (const float*)d_in[16];
    const float* p1_ab2   = (const float*)d_in[17];
    const float* p1_eW1   = (const float*)d_in[18];
    const float* p1_eb1   = (const float*)d_in[19];
    const float* p1_eW2   = (const float*)d_in[20];
    const float* p1_eb2   = (const float*)d_in[21];
    const float* p1_theta = (const float*)d_in[22];
    const float* p1_bias  = (const float*)d_in[23];

    float* ws = (float*)d_ws;
    float* proj0 = ws;
    float* proj1 = ws;                         // aliases proj0 (layer-0 proj dead by then)
    float* x1    = ws + 15360000;
    float* out = (float*)d_out;

    const int EB = E_EDGES / TE;  // 12500 blocks

    // ---- layer 0 ----
    gemm_proj<64><<<N_NODES / 16, 256, 0, stream>>>(x0, p0_Wp, proj0);
    init_x1<<<(N_NODES * 256 + 255) / 256, 256, 0, stream>>>(proj0, p0_theta, p0_bias, x1);
    fused_edge<0><<<EB, 256, 0, stream>>>(proj0, ei, p0_aW1, p0_ab1, p0_aW2, p0_ab2,
                                          p0_eW1, p0_eb1, p0_eW2, p0_eb2, x1);
    sigmoid_k<<<(M1 * 64 + 255) / 256, 256, 0, stream>>>((float4*)x1, M1 * 64);

    // ---- layer 1 ----
    gemm_proj<256><<<M1 / 16, 256, 0, stream>>>(x1, p1_Wp, proj1);
    init_out<<<(M1 * 64 + 255) / 256, 256, 0, stream>>>(proj1, p1_theta, p1_bias, out);
    fused_edge<1><<<EB, 256, 0, stream>>>(proj1, ei, p1_aW1, p1_ab1, p1_aW2, p1_ab2,
                                          p1_eW1, p1_eb1, p1_eW2, p1_eb2, out);
}

// Round 4
// 3625.819 us; speedup vs baseline: 8.5488x; 1.2334x over previous
//
#include <hip/hip_runtime.h>
#include <math.h>

#define N_NODES 20000
#define E_EDGES 200000
#define M1 60000            // layer-1 node count (3*N)
#define TE 16               // edges per block in fused kernel
#define TPAD 68             // padded tile row length (floats), 16B-aligned, breaks bank conflicts

// ---------------------------------------------------------------------------
// GEMM: C[M,256] = X[M,K] @ W[K,256]   (K = 64 or 256, M multiple of 16)
// block 256: rg=tid>>6 owns rows rg*4..+3, j0=(tid&63)*4 owns 4 contiguous cols.
// W loads and C stores are float4, 1KB/wave coalesced.
// ---------------------------------------------------------------------------
template<int K>
__global__ __launch_bounds__(256) void gemm_proj(const float* __restrict__ X,
                                                 const float* __restrict__ W,
                                                 float* __restrict__ C) {
    __shared__ float Xs[16][K];
    const int row0 = blockIdx.x * 16;
    const int tid = threadIdx.x;
    for (int i4 = tid; i4 < 16 * K / 4; i4 += 256) {
        int r = i4 / (K / 4), kq = i4 - r * (K / 4);
        ((float4*)&Xs[r][0])[kq] = ((const float4*)(X + (size_t)(row0 + r) * K))[kq];
    }
    __syncthreads();
    const int rg = tid >> 6;
    const int j0 = (tid & 63) * 4;
    float acc[4][4];
#pragma unroll
    for (int r = 0; r < 4; ++r)
#pragma unroll
        for (int t = 0; t < 4; ++t) acc[r][t] = 0.f;
#pragma unroll 4
    for (int k = 0; k < K; ++k) {
        float4 wq = *(const float4*)(W + (size_t)k * 256 + j0);
#pragma unroll
        for (int r = 0; r < 4; ++r) {
            float xv = Xs[rg * 4 + r][k];
            acc[r][0] = fmaf(xv, wq.x, acc[r][0]);
            acc[r][1] = fmaf(xv, wq.y, acc[r][1]);
            acc[r][2] = fmaf(xv, wq.z, acc[r][2]);
            acc[r][3] = fmaf(xv, wq.w, acc[r][3]);
        }
    }
#pragma unroll
    for (int r = 0; r < 4; ++r)
        *(float4*)(C + (size_t)(row0 + rg * 4 + r) * 256 + j0) =
            make_float4(acc[r][0], acc[r][1], acc[r][2], acc[r][3]);
}

__global__ void init_x1(const float* __restrict__ proj0,
                        const float* __restrict__ theta,
                        const float* __restrict__ bias,
                        float* __restrict__ x1) {
    int idx = blockIdx.x * 256 + threadIdx.x;
    if (idx >= N_NODES * 256) return;
    int c = idx & 255;
    float v = theta[c] * proj0[idx] + bias[c];
    x1[idx] = v;
    x1[N_NODES * 256 + idx] = v;
    x1[2 * N_NODES * 256 + idx] = v;
}

__global__ void init_out(const float* __restrict__ proj1,
                         const float* __restrict__ theta,
                         const float* __restrict__ bias,
                         float* __restrict__ out) {
    int idx = blockIdx.x * 256 + threadIdx.x;
    if (idx >= M1 * 64) return;
    int v = idx >> 6, f = idx & 63;
    float s = 0.f;
#pragma unroll
    for (int h = 0; h < 4; ++h) s += theta[h * 64 + f] * proj1[v * 256 + h * 64 + f];
    float val = 0.25f * s + bias[f];
    out[idx] = val;
    out[M1 * 64 + idx] = val;
    out[2 * M1 * 64 + idx] = val;
}

__global__ void sigmoid_k(float4* __restrict__ x, int n4) {
    int i = blockIdx.x * 256 + threadIdx.x;
    if (i >= n4) return;
    float4 v = x[i];
    v.x = 1.f / (1.f + expf(-v.x));
    v.y = 1.f / (1.f + expf(-v.y));
    v.z = 1.f / (1.f + expf(-v.z));
    v.w = 1.f / (1.f + expf(-v.w));
    x[i] = v;
}

// ---------------------------------------------------------------------------
// One 64-wide K-section: A from LDS (rows padded TPAD), W streamed from
// global (L1/L2-resident; 4-way ty-broadcast, 256B/wave coalesced loads).
// acc[r][c] += sum_k A[ty*4+r][k] * W[k][tx*4+c]
// ---------------------------------------------------------------------------
__device__ __forceinline__ void fma_rank1(float acc[4], float a, const float4 w) {
    acc[0] = fmaf(a, w.x, acc[0]);
    acc[1] = fmaf(a, w.y, acc[1]);
    acc[2] = fmaf(a, w.z, acc[2]);
    acc[3] = fmaf(a, w.w, acc[3]);
}

__device__ __forceinline__ void gemm_sec(const float* A,
                                         const float* __restrict__ Wg,
                                         int ty, int tx, float acc[4][4]) {
#pragma unroll 4
    for (int k = 0; k < 64; k += 4) {
        float4 a0 = *(const float4*)(A + (ty * 4 + 0) * TPAD + k);
        float4 a1 = *(const float4*)(A + (ty * 4 + 1) * TPAD + k);
        float4 a2 = *(const float4*)(A + (ty * 4 + 2) * TPAD + k);
        float4 a3 = *(const float4*)(A + (ty * 4 + 3) * TPAD + k);
        float4 w0 = *(const float4*)(Wg + (k + 0) * 64 + tx * 4);
        float4 w1 = *(const float4*)(Wg + (k + 1) * 64 + tx * 4);
        float4 w2 = *(const float4*)(Wg + (k + 2) * 64 + tx * 4);
        float4 w3 = *(const float4*)(Wg + (k + 3) * 64 + tx * 4);
        fma_rank1(acc[0], a0.x, w0); fma_rank1(acc[0], a0.y, w1);
        fma_rank1(acc[0], a0.z, w2); fma_rank1(acc[0], a0.w, w3);
        fma_rank1(acc[1], a1.x, w0); fma_rank1(acc[1], a1.y, w1);
        fma_rank1(acc[1], a1.z, w2); fma_rank1(acc[1], a1.w, w3);
        fma_rank1(acc[2], a2.x, w0); fma_rank1(acc[2], a2.y, w1);
        fma_rank1(acc[2], a2.z, w2); fma_rank1(acc[2], a2.w, w3);
        fma_rank1(acc[3], a3.x, w0); fma_rank1(acc[3], a3.y, w1);
        fma_rank1(acc[3], a3.z, w2); fma_rank1(acc[3], a3.w, w3);
    }
}

// ---------------------------------------------------------------------------
// Fused edge kernel. Block: 16 edges, 64 rows (row = e*4+h), 256 threads.
// LDS = tiles (52KB) + nb1 (17KB) = 69.6KB -> 2 blocks/CU, 2 waves/SIMD.
// Weights stream from global (L2); per-block weight traffic ~192KB.
// ---------------------------------------------------------------------------
template<int LAYER>
__global__ __launch_bounds__(256, 2) void fused_edge(const float* __restrict__ proj,
                                                     const int* __restrict__ ei,
                                                     const float* __restrict__ aW1,
                                                     const float* __restrict__ ab1,
                                                     const float* __restrict__ aW2,
                                                     const float* __restrict__ ab2,
                                                     const float* __restrict__ eW1,
                                                     const float* __restrict__ eb1,
                                                     const float* __restrict__ eW2,
                                                     const float* __restrict__ eb2,
                                                     float* __restrict__ out) {
    __shared__ float sT[3][64 * TPAD];   // gathered d,m,s tiles (rows padded)
    __shared__ float nb1s[64 * TPAD];    // pair-MLP hidden

    const int tid = threadIdx.x;
    const int ty = tid >> 4, tx = tid & 15;
    const int wv = tid >> 6, lane = tid & 63;
    const int e0 = blockIdx.x * TE;

    // ---- gather d/m/s: 48 segments (role,edge), each one 1KB proj row ----
    for (int seg = wv; seg < 48; seg += 4) {
        const int ro = seg >> 4, e = seg & 15;
        const int v = ei[ro * E_EDGES + e0 + e];
        const float4 src = *(const float4*)(proj + (size_t)v * 256 + lane * 4);
        *(float4*)(&sT[ro][(e * 4 + (lane >> 4)) * TPAD + (lane & 15) * 4]) = src;
    }
    __syncthreads();

    // ---- attention MLP: acc = inter @ aW1 (K=192) ----
    float acc[4][4];
#pragma unroll
    for (int r = 0; r < 4; ++r)
#pragma unroll
        for (int c = 0; c < 4; ++c) acc[r][c] = 0.f;
    for (int ks = 0; ks < 3; ++ks)
        gemm_sec(sT[ks], aW1 + ks * 4096, ty, tx, acc);

    // epilogue: +ab1, relu, @aW2, allreduce over tx, +ab2, leaky, softmax
    float alr[4];
    {
        float b1c[4], w2c[4];
#pragma unroll
        for (int c = 0; c < 4; ++c) { b1c[c] = ab1[tx * 4 + c]; w2c[c] = aW2[tx * 4 + c]; }
        float p_[4];
#pragma unroll
        for (int r = 0; r < 4; ++r) {
            float s = 0.f;
#pragma unroll
            for (int c = 0; c < 4; ++c) {
                float hv = fmaxf(acc[r][c] + b1c[c], 0.f);
                s = fmaf(hv, w2c[c], s);
            }
            p_[r] = s;
        }
#pragma unroll
        for (int off = 1; off < 16; off <<= 1) {
#pragma unroll
            for (int r = 0; r < 4; ++r) p_[r] += __shfl_xor(p_[r], off);
        }
        const float b2 = ab2[0];
        float sc[4];
#pragma unroll
        for (int r = 0; r < 4; ++r) {
            float v = p_[r] + b2;
            sc[r] = (v >= 0.f) ? v : 0.2f * v;
        }
        float mx = fmaxf(fmaxf(sc[0], sc[1]), fmaxf(sc[2], sc[3]));
        float ex[4], sum = 0.f;
#pragma unroll
        for (int r = 0; r < 4; ++r) { ex[r] = expf(sc[r] - mx); sum += ex[r]; }
        float inv = 1.f / sum;
#pragma unroll
        for (int r = 0; r < 4; ++r) alr[r] = ex[r] * inv;
    }

    // this thread's edge node ids
    const int vd = ei[e0 + ty];
    const int vm = ei[E_EDGES + e0 + ty];
    const int vs = ei[2 * E_EDGES + e0 + ty];
    const int vt[3] = {vd, vm, vs};

    float eb1c[4], eb2c[4];
#pragma unroll
    for (int c = 0; c < 4; ++c) { eb1c[c] = eb1[tx * 4 + c]; eb2c[c] = eb2[tx * 4 + c]; }

#pragma unroll 1
    for (int p = 0; p < 3; ++p) {
        // pairs: p0=(m,s) p1=(d,s) p2=(d,m)
        const float* Asec = (p == 0) ? sT[1] : sT[0];
        const float* Bsec = (p == 2) ? sT[1] : sT[2];
        float a1[4][4];
#pragma unroll
        for (int r = 0; r < 4; ++r)
#pragma unroll
            for (int c = 0; c < 4; ++c) a1[r][c] = 0.f;
        gemm_sec(Asec, eW1, ty, tx, a1);
        gemm_sec(Bsec, eW1 + 4096, ty, tx, a1);
        // bias + leaky -> nb1
#pragma unroll
        for (int r = 0; r < 4; ++r) {
            float4 v;
            float t0 = a1[r][0] + eb1c[0]; v.x = (t0 >= 0.f) ? t0 : 0.2f * t0;
            float t1 = a1[r][1] + eb1c[1]; v.y = (t1 >= 0.f) ? t1 : 0.2f * t1;
            float t2 = a1[r][2] + eb1c[2]; v.z = (t2 >= 0.f) ? t2 : 0.2f * t2;
            float t3 = a1[r][3] + eb1c[3]; v.w = (t3 >= 0.f) ? t3 : 0.2f * t3;
            *(float4*)(&nb1s[(ty * 4 + r) * TPAD + tx * 4]) = v;
        }
        __syncthreads();
        float a2[4][4];
#pragma unroll
        for (int r = 0; r < 4; ++r)
#pragma unroll
            for (int c = 0; c < 4; ++c) a2[r][c] = 0.f;
        gemm_sec(nb1s, eW2, ty, tx, a2);
        // alpha-weighted scatter
        if (LAYER == 0) {
            float* dst = out + ((size_t)(p * N_NODES + vt[p])) * 256 + tx * 4;
#pragma unroll
            for (int r = 0; r < 4; ++r)
#pragma unroll
                for (int c = 0; c < 4; ++c)
                    atomicAdd(dst + r * 64 + c, alr[r] * (a2[r][c] + eb2c[c]));
        } else {
            float* dst = out + ((size_t)(p * M1 + vt[p])) * 64 + tx * 4;
#pragma unroll
            for (int c = 0; c < 4; ++c) {
                float s = 0.f;
#pragma unroll
                for (int r = 0; r < 4; ++r) s += alr[r] * (a2[r][c] + eb2c[c]);
                atomicAdd(dst + c, 0.25f * s);
            }
        }
        __syncthreads();  // nb1 reused next pair
    }
}

// ---------------------------------------------------------------------------
extern "C" void kernel_launch(void* const* d_in, const int* in_sizes, int n_in,
                              void* d_out, int out_size, void* d_ws, size_t ws_size,
                              hipStream_t stream) {
    (void)in_sizes; (void)n_in; (void)out_size; (void)ws_size;
    const float* x0       = (const float*)d_in[0];
    const int* ei         = (const int*)d_in[1];
    const float* p0_Wp    = (const float*)d_in[2];
    const float* p0_aW1   = (const float*)d_in[3];
    const float* p0_ab1   = (const float*)d_in[4];
    const float* p0_aW2   = (const float*)d_in[5];
    const float* p0_ab2   = (const float*)d_in[6];
    const float* p0_eW1   = (const float*)d_in[7];
    const float* p0_eb1   = (const float*)d_in[8];
    const float* p0_eW2   = (const float*)d_in[9];
    const float* p0_eb2   = (const float*)d_in[10];
    const float* p0_theta = (const float*)d_in[11];
    const float* p0_bias  = (const float*)d_in[12];
    const float* p1_Wp    = (const float*)d_in[13];
    const float* p1_aW1   = (const float*)d_in[14];
    const float* p1_ab1   = (const float*)d_in[15];
    const float* p1_aW2   = (const float*)d_in[16];
    const float* p1_ab2   = (const float*)d_in[17];
    const float* p1_eW1   = (const float*)d_in[18];
    const float* p1_eb1   = (const float*)d_in[19];
    const float* p1_eW2   = (const float*)d_in[20];
    const float* p1_eb2   = (const float*)d_in[21];
    const float* p1_theta = (const float*)d_in[22];
    const float* p1_bias  = (const float*)d_in[23];

    float* ws = (float*)d_ws;
    float* proj0 = ws;
    float* proj1 = ws;                         // aliases proj0 (layer-0 proj dead by then)
    float* x1    = ws + 15360000;
    float* out = (float*)d_out;

    const int EB = E_EDGES / TE;  // 12500 blocks

    // ---- layer 0 ----
    gemm_proj<64><<<N_NODES / 16, 256, 0, stream>>>(x0, p0_Wp, proj0);
    init_x1<<<(N_NODES * 256 + 255) / 256, 256, 0, stream>>>(proj0, p0_theta, p0_bias, x1);
    fused_edge<0><<<EB, 256, 0, stream>>>(proj0, ei, p0_aW1, p0_ab1, p0_aW2, p0_ab2,
                                          p0_eW1, p0_eb1, p0_eW2, p0_eb2, x1);
    sigmoid_k<<<(M1 * 64 + 255) / 256, 256, 0, stream>>>((float4*)x1, M1 * 64);

    // ---- layer 1 ----
    gemm_proj<256><<<M1 / 16, 256, 0, stream>>>(x1, p1_Wp, proj1);
    init_out<<<(M1 * 64 + 255) / 256, 256, 0, stream>>>(proj1, p1_theta, p1_bias, out);
    fused_edge<1><<<EB, 256, 0, stream>>>(proj1, ei, p1_aW1, p1_ab1, p1_aW2, p1_ab2,
                                          p1_eW1, p1_eb1, p1_eW2, p1_eb2, out);
}

// Round 5
// 1218.868 us; speedup vs baseline: 25.4306x; 2.9747x over previous
//
#include <hip/hip_runtime.h>
#include <math.h>

#define N_NODES 20000
#define E_EDGES 200000
#define M1 60000            // layer-1 node count (3*N)
#define TE 16               // edges per block in fused kernel

typedef __attribute__((ext_vector_type(8))) short short8;
typedef __attribute__((ext_vector_type(4))) float f32x4;

// float -> bf16 (round-to-nearest-even), bit-level
__device__ __forceinline__ unsigned short f2bf(float f) {
    union { float f; unsigned int u; } v; v.f = f;
    unsigned int r = v.u + 0x7fffu + ((v.u >> 16) & 1u);
    return (unsigned short)(r >> 16);
}

// load 8 consecutive fp32 from global, pack to 8 bf16 (one MFMA A-frag slice)
__device__ __forceinline__ short8 ldA(const float* p) {
    float4 f0 = *(const float4*)p;
    float4 f1 = *(const float4*)(p + 4);
    short8 r;
    r[0] = (short)f2bf(f0.x); r[1] = (short)f2bf(f0.y);
    r[2] = (short)f2bf(f0.z); r[3] = (short)f2bf(f0.w);
    r[4] = (short)f2bf(f1.x); r[5] = (short)f2bf(f1.y);
    r[6] = (short)f2bf(f1.z); r[7] = (short)f2bf(f1.w);
    return r;
}

// ---------------------------------------------------------------------------
// GEMM: C[M,256] = X[M,K] @ W[K,256]  (fp32, unchanged from round 4)
// ---------------------------------------------------------------------------
template<int K>
__global__ __launch_bounds__(256) void gemm_proj(const float* __restrict__ X,
                                                 const float* __restrict__ W,
                                                 float* __restrict__ C) {
    __shared__ float Xs[16][K];
    const int row0 = blockIdx.x * 16;
    const int tid = threadIdx.x;
    for (int i4 = tid; i4 < 16 * K / 4; i4 += 256) {
        int r = i4 / (K / 4), kq = i4 - r * (K / 4);
        ((float4*)&Xs[r][0])[kq] = ((const float4*)(X + (size_t)(row0 + r) * K))[kq];
    }
    __syncthreads();
    const int rg = tid >> 6;
    const int j0 = (tid & 63) * 4;
    float acc[4][4];
#pragma unroll
    for (int r = 0; r < 4; ++r)
#pragma unroll
        for (int t = 0; t < 4; ++t) acc[r][t] = 0.f;
#pragma unroll 4
    for (int k = 0; k < K; ++k) {
        float4 wq = *(const float4*)(W + (size_t)k * 256 + j0);
#pragma unroll
        for (int r = 0; r < 4; ++r) {
            float xv = Xs[rg * 4 + r][k];
            acc[r][0] = fmaf(xv, wq.x, acc[r][0]);
            acc[r][1] = fmaf(xv, wq.y, acc[r][1]);
            acc[r][2] = fmaf(xv, wq.z, acc[r][2]);
            acc[r][3] = fmaf(xv, wq.w, acc[r][3]);
        }
    }
#pragma unroll
    for (int r = 0; r < 4; ++r)
        *(float4*)(C + (size_t)(row0 + rg * 4 + r) * 256 + j0) =
            make_float4(acc[r][0], acc[r][1], acc[r][2], acc[r][3]);
}

__global__ void init_x1(const float* __restrict__ proj0,
                        const float* __restrict__ theta,
                        const float* __restrict__ bias,
                        float* __restrict__ x1) {
    int idx = blockIdx.x * 256 + threadIdx.x;
    if (idx >= N_NODES * 256) return;
    int c = idx & 255;
    float v = theta[c] * proj0[idx] + bias[c];
    x1[idx] = v;
    x1[N_NODES * 256 + idx] = v;
    x1[2 * N_NODES * 256 + idx] = v;
}

__global__ void init_out(const float* __restrict__ proj1,
                         const float* __restrict__ theta,
                         const float* __restrict__ bias,
                         float* __restrict__ out) {
    int idx = blockIdx.x * 256 + threadIdx.x;
    if (idx >= M1 * 64) return;
    int v = idx >> 6, f = idx & 63;
    float s = 0.f;
#pragma unroll
    for (int h = 0; h < 4; ++h) s += theta[h * 64 + f] * proj1[v * 256 + h * 64 + f];
    float val = 0.25f * s + bias[f];
    out[idx] = val;
    out[M1 * 64 + idx] = val;
    out[2 * M1 * 64 + idx] = val;
}

__global__ void sigmoid_k(float4* __restrict__ x, int n4) {
    int i = blockIdx.x * 256 + threadIdx.x;
    if (i >= n4) return;
    float4 v = x[i];
    v.x = 1.f / (1.f + expf(-v.x));
    v.y = 1.f / (1.f + expf(-v.y));
    v.z = 1.f / (1.f + expf(-v.z));
    v.w = 1.f / (1.f + expf(-v.w));
    x[i] = v;
}

// ---------------------------------------------------------------------------
// Weight prep: W[K][64] fp32 -> WT[64][K] bf16 (transpose + convert)
// ---------------------------------------------------------------------------
__global__ void prep_wt(const float* __restrict__ W, unsigned short* __restrict__ WT,
                        int K) {
    int i = blockIdx.x * 256 + threadIdx.x;
    if (i >= 64 * K) return;
    int c = i / K, k = i - c * K;
    WT[i] = f2bf(W[k * 64 + c]);
}

// ---------------------------------------------------------------------------
// One pair MLP: a1 = leaky(concat(A0,A1) @ eW1 + eb1); a2 = a1 @ eW2;
// scatter alpha-weighted (LAYER0: per-head atomics; LAYER1: head-mean).
// nb: per-wave LDS scratch [16 rows][64 cols] bf16, XOR-chunk-swizzled.
// ---------------------------------------------------------------------------
template<int LAYER>
__device__ __forceinline__ void do_pair(int p,
                                        const short8 A0[2], const short8 A1[2],
                                        const unsigned short* __restrict__ eW1t,
                                        const unsigned short* __restrict__ eW2t,
                                        const float eb1c[4], const float eb2c[4],
                                        const float alpha[4],
                                        unsigned short* nb,
                                        int g, int t, int ko, int vtp,
                                        float* __restrict__ out) {
    const f32x4 z = {0.f, 0.f, 0.f, 0.f};
    f32x4 a1[4] = {z, z, z, z};
#pragma unroll
    for (int half = 0; half < 2; ++half) {
#pragma unroll
        for (int ks = 0; ks < 2; ++ks) {
            short8 a = half ? A1[ks] : A0[ks];
#pragma unroll
            for (int f = 0; f < 4; ++f) {
                short8 b = *(const short8*)(eW1t + (16 * f + t) * 128 + half * 64 + ks * 32 + ko);
                a1[f] = __builtin_amdgcn_mfma_f32_16x16x32_bf16(a, b, a1[f], 0, 0, 0);
            }
        }
    }
    // bias + leaky -> per-wave LDS (bf16, swizzled: chunk ^= row&7)
#pragma unroll
    for (int f = 0; f < 4; ++f) {
        const int col = 16 * f + t;
#pragma unroll
        for (int r = 0; r < 4; ++r) {
            const int row = 4 * g + r;
            float hv = a1[f][r] + eb1c[f];
            hv = (hv >= 0.f) ? hv : 0.2f * hv;
            const int chunk = (col >> 3) ^ (row & 7);
            nb[row * 64 + chunk * 8 + (col & 7)] = f2bf(hv);
        }
    }
    // a2 = nb @ eW2
    f32x4 a2[4] = {z, z, z, z};
#pragma unroll
    for (int ks = 0; ks < 2; ++ks) {
        const int chunk = (ks * 4 + g) ^ (t & 7);
        short8 a = *(const short8*)(nb + t * 64 + chunk * 8);
#pragma unroll
        for (int f = 0; f < 4; ++f) {
            short8 b = *(const short8*)(eW2t + (16 * f + t) * 64 + ks * 32 + ko);
            a2[f] = __builtin_amdgcn_mfma_f32_16x16x32_bf16(a, b, a2[f], 0, 0, 0);
        }
    }
    // scatter
    if (LAYER == 0) {
#pragma unroll
        for (int f = 0; f < 4; ++f) {
            float* dst = out + ((size_t)(p * N_NODES + vtp)) * 256 + 16 * f + t;
#pragma unroll
            for (int r = 0; r < 4; ++r)
                atomicAdd(dst + r * 64, alpha[r] * (a2[f][r] + eb2c[f]));
        }
    } else {
#pragma unroll
        for (int f = 0; f < 4; ++f) {
            float s = 0.f;
#pragma unroll
            for (int r = 0; r < 4; ++r) s += alpha[r] * (a2[f][r] + eb2c[f]);
            atomicAdd(out + ((size_t)(p * M1 + vtp)) * 64 + 16 * f + t, 0.25f * s);
        }
    }
}

// ---------------------------------------------------------------------------
// Fused edge kernel (MFMA). Block: 16 edges, 4 waves; wave = 4 edges = 16 rows.
// No block-level barriers; LDS = 8KB per-wave hidden scratch.
// ---------------------------------------------------------------------------
template<int LAYER>
__global__ __launch_bounds__(256) void fused_edge(const float* __restrict__ proj,
                                                  const int* __restrict__ ei,
                                                  const unsigned short* __restrict__ aW1t,
                                                  const float* __restrict__ ab1,
                                                  const float* __restrict__ aW2,
                                                  const float* __restrict__ ab2,
                                                  const unsigned short* __restrict__ eW1t,
                                                  const float* __restrict__ eb1,
                                                  const unsigned short* __restrict__ eW2t,
                                                  const float* __restrict__ eb2,
                                                  float* __restrict__ out) {
    __shared__ __align__(16) unsigned short nb1[4][16 * 64];

    const int tid = threadIdx.x;
    const int w = tid >> 6, lane = tid & 63;
    const int g = lane >> 4, t = lane & 15;
    const int e0 = blockIdx.x * TE + w * 4;
    const int ko = g * 8;             // this lane's k-offset inside a 32-k step

    // A-side: lane supplies row t -> edge e0+(t>>2), head t&3
    const int ea = e0 + (t >> 2);
    const int head = t & 3;
    const float* baseD = proj + (size_t)ei[ea] * 256 + head * 64;
    const float* baseM = proj + (size_t)ei[E_EDGES + ea] * 256 + head * 64;
    const float* baseS = proj + (size_t)ei[2 * E_EDGES + ea] * 256 + head * 64;

    // C-side: lane's output rows are 4g..4g+3 -> edge e0+g, heads 0..3
    const int ec = e0 + g;
    const int vt0 = ei[ec], vt1 = ei[E_EDGES + ec], vt2 = ei[2 * E_EDGES + ec];

    // preload + convert this lane's A slices (16 bf16 per role)
    short8 aD[2], aM[2], aS[2];
#pragma unroll
    for (int ks = 0; ks < 2; ++ks) {
        aD[ks] = ldA(baseD + ks * 32 + ko);
        aM[ks] = ldA(baseM + ks * 32 + ko);
        aS[ks] = ldA(baseS + ks * 32 + ko);
    }

    // per-lane column constants
    float ab1c[4], aW2c[4], eb1c[4], eb2c[4];
#pragma unroll
    for (int f = 0; f < 4; ++f) {
        ab1c[f] = ab1[16 * f + t];
        aW2c[f] = aW2[16 * f + t];
        eb1c[f] = eb1[16 * f + t];
        eb2c[f] = eb2[16 * f + t];
    }

    // ---- attention MLP: H = [d|m|s] @ aW1  (K=192) ----
    const f32x4 z = {0.f, 0.f, 0.f, 0.f};
    f32x4 acc[4] = {z, z, z, z};
#pragma unroll
    for (int ks = 0; ks < 2; ++ks) {
        short8 a = aD[ks];
#pragma unroll
        for (int f = 0; f < 4; ++f) {
            short8 b = *(const short8*)(aW1t + (16 * f + t) * 192 + 0 * 64 + ks * 32 + ko);
            acc[f] = __builtin_amdgcn_mfma_f32_16x16x32_bf16(a, b, acc[f], 0, 0, 0);
        }
    }
#pragma unroll
    for (int ks = 0; ks < 2; ++ks) {
        short8 a = aM[ks];
#pragma unroll
        for (int f = 0; f < 4; ++f) {
            short8 b = *(const short8*)(aW1t + (16 * f + t) * 192 + 1 * 64 + ks * 32 + ko);
            acc[f] = __builtin_amdgcn_mfma_f32_16x16x32_bf16(a, b, acc[f], 0, 0, 0);
        }
    }
#pragma unroll
    for (int ks = 0; ks < 2; ++ks) {
        short8 a = aS[ks];
#pragma unroll
        for (int f = 0; f < 4; ++f) {
            short8 b = *(const short8*)(aW1t + (16 * f + t) * 192 + 2 * 64 + ks * 32 + ko);
            acc[f] = __builtin_amdgcn_mfma_f32_16x16x32_bf16(a, b, acc[f], 0, 0, 0);
        }
    }

    // ---- score epilogue: relu, @aW2 (col-reduce), +ab2, leaky, softmax ----
    float alpha[4];
    {
        float p_[4];
#pragma unroll
        for (int r = 0; r < 4; ++r) {
            float s = 0.f;
#pragma unroll
            for (int f = 0; f < 4; ++f) {
                float hv = fmaxf(acc[f][r] + ab1c[f], 0.f);
                s = fmaf(hv, aW2c[f], s);
            }
            p_[r] = s;
        }
#pragma unroll
        for (int off = 1; off < 16; off <<= 1) {
#pragma unroll
            for (int r = 0; r < 4; ++r) p_[r] += __shfl_xor(p_[r], off);
        }
        const float b2 = ab2[0];
        float sc[4];
#pragma unroll
        for (int r = 0; r < 4; ++r) {
            float v = p_[r] + b2;
            sc[r] = (v >= 0.f) ? v : 0.2f * v;
        }
        float mx = fmaxf(fmaxf(sc[0], sc[1]), fmaxf(sc[2], sc[3]));
        float ex[4], sum = 0.f;
#pragma unroll
        for (int r = 0; r < 4; ++r) { ex[r] = expf(sc[r] - mx); sum += ex[r]; }
        float inv = 1.f / sum;
#pragma unroll
        for (int r = 0; r < 4; ++r) alpha[r] = ex[r] * inv;
    }

    // ---- 3 pair MLPs + scatter (p0=(m,s)->d, p1=(d,s)->m, p2=(d,m)->s) ----
    unsigned short* nb = &nb1[w][0];
    do_pair<LAYER>(0, aM, aS, eW1t, eW2t, eb1c, eb2c, alpha, nb, g, t, ko, vt0, out);
    do_pair<LAYER>(1, aD, aS, eW1t, eW2t, eb1c, eb2c, alpha, nb, g, t, ko, vt1, out);
    do_pair<LAYER>(2, aD, aM, eW1t, eW2t, eb1c, eb2c, alpha, nb, g, t, ko, vt2, out);
}

// ---------------------------------------------------------------------------
extern "C" void kernel_launch(void* const* d_in, const int* in_sizes, int n_in,
                              void* d_out, int out_size, void* d_ws, size_t ws_size,
                              hipStream_t stream) {
    (void)in_sizes; (void)n_in; (void)out_size; (void)ws_size;
    const float* x0       = (const float*)d_in[0];
    const int* ei         = (const int*)d_in[1];
    const float* p0_Wp    = (const float*)d_in[2];
    const float* p0_aW1   = (const float*)d_in[3];
    const float* p0_ab1   = (const float*)d_in[4];
    const float* p0_aW2   = (const float*)d_in[5];
    const float* p0_ab2   = (const float*)d_in[6];
    const float* p0_eW1   = (const float*)d_in[7];
    const float* p0_eb1   = (const float*)d_in[8];
    const float* p0_eW2   = (const float*)d_in[9];
    const float* p0_eb2   = (const float*)d_in[10];
    const float* p0_theta = (const float*)d_in[11];
    const float* p0_bias  = (const float*)d_in[12];
    const float* p1_Wp    = (const float*)d_in[13];
    const float* p1_aW1   = (const float*)d_in[14];
    const float* p1_ab1   = (const float*)d_in[15];
    const float* p1_aW2   = (const float*)d_in[16];
    const float* p1_ab2   = (const float*)d_in[17];
    const float* p1_eW1   = (const float*)d_in[18];
    const float* p1_eb1   = (const float*)d_in[19];
    const float* p1_eW2   = (const float*)d_in[20];
    const float* p1_eb2   = (const float*)d_in[21];
    const float* p1_theta = (const float*)d_in[22];
    const float* p1_bias  = (const float*)d_in[23];

    // ws: [proj0|proj1 alias: 15.36M f][x1: 15.36M f][bf16 weights: 49152 us]
    float* ws = (float*)d_ws;
    float* proj0 = ws;
    float* proj1 = ws;
    float* x1    = ws + 15360000;
    unsigned short* wt = (unsigned short*)(ws + 30720000);
    unsigned short* w0a  = wt;               // aW1^T  64x192
    unsigned short* w0e1 = wt + 12288;       // eW1^T  64x128
    unsigned short* w0e2 = wt + 20480;       // eW2^T  64x64
    unsigned short* w1a  = wt + 24576;
    unsigned short* w1e1 = wt + 36864;
    unsigned short* w1e2 = wt + 45056;
    float* out = (float*)d_out;

    const int EB = E_EDGES / TE;  // 12500 blocks

    // ---- weight prep (bf16 transposes) ----
    prep_wt<<<(64 * 192 + 255) / 256, 256, 0, stream>>>(p0_aW1, w0a, 192);
    prep_wt<<<(64 * 128 + 255) / 256, 256, 0, stream>>>(p0_eW1, w0e1, 128);
    prep_wt<<<(64 * 64 + 255) / 256, 256, 0, stream>>>(p0_eW2, w0e2, 64);
    prep_wt<<<(64 * 192 + 255) / 256, 256, 0, stream>>>(p1_aW1, w1a, 192);
    prep_wt<<<(64 * 128 + 255) / 256, 256, 0, stream>>>(p1_eW1, w1e1, 128);
    prep_wt<<<(64 * 64 + 255) / 256, 256, 0, stream>>>(p1_eW2, w1e2, 64);

    // ---- layer 0 ----
    gemm_proj<64><<<N_NODES / 16, 256, 0, stream>>>(x0, p0_Wp, proj0);
    init_x1<<<(N_NODES * 256 + 255) / 256, 256, 0, stream>>>(proj0, p0_theta, p0_bias, x1);
    fused_edge<0><<<EB, 256, 0, stream>>>(proj0, ei, w0a, p0_ab1, p0_aW2, p0_ab2,
                                          w0e1, p0_eb1, w0e2, p0_eb2, x1);
    sigmoid_k<<<(M1 * 64 + 255) / 256, 256, 0, stream>>>((float4*)x1, M1 * 64);

    // ---- layer 1 ----
    gemm_proj<256><<<M1 / 16, 256, 0, stream>>>(x1, p1_Wp, proj1);
    init_out<<<(M1 * 64 + 255) / 256, 256, 0, stream>>>(proj1, p1_theta, p1_bias, out);
    fused_edge<1><<<EB, 256, 0, stream>>>(proj1, ei, w1a, p1_ab1, p1_aW2, p1_ab2,
                                          w1e1, p1_eb1, w1e2, p1_eb2, out);
}